// Round 5
// baseline (53978.687 us; speedup 1.0000x reference)
//
#include <hip/hip_runtime.h>
#include <cmath>

#define NN 1024
#define DD 1024
#define BB 8
#define LL 4
#define OUTD (DD*(LL+1))   // 5120
#define NB 32
#define NPAN (NN/NB)       // 32
#define BSTR ((size_t)NN*OUTD)

typedef short b8v __attribute__((ext_vector_type(8)));
typedef float f4v __attribute__((ext_vector_type(4)));

__device__ __forceinline__ unsigned short f2bf(float x){
  unsigned u=__float_as_uint(x);
  return (unsigned short)((u + 0x7FFFu + ((u>>16)&1u))>>16);
}
__device__ __forceinline__ float bf2f(unsigned short h){
  return __uint_as_float(((unsigned)h)<<16);
}
// 3-split: x = h + m + l + O(2^-25 x)  -> 6-product MFMA ~= fp32 precision
__device__ __forceinline__ void bsplit3(float x, short& h, short& m, short& l){
  unsigned short hh=f2bf(x);
  float r1=x-bf2f(hh);          // exact (Sterbenz)
  unsigned short mm=f2bf(r1);
  float r2=r1-bf2f(mm);         // exact
  h=(short)hh; m=(short)mm; l=(short)f2bf(r2);
}

// ---------------- setup kernels ----------------
__global__ void k_deg_init(float* degF){ degF[threadIdx.x]=0.f; }

__global__ void k_deg(const int* __restrict__ ei, float* __restrict__ degF, int E){
  int e=blockIdx.x*blockDim.x+threadIdx.x;
  if(e<E) atomicAdd(&degF[ei[2*e]],1.f);
}

__global__ void k_scan(const float* __restrict__ degF, float* __restrict__ isq, int* __restrict__ rowoff){
  __shared__ int s[NN];
  int i=threadIdx.x;
  int d=(int)degF[i];
  s[i]=d; __syncthreads();
  for(int off=1;off<NN;off<<=1){
    int v=(i>=off)?s[i-off]:0;
    __syncthreads();
    s[i]+=v;
    __syncthreads();
  }
  if(i==0) rowoff[0]=0;
  rowoff[i+1]=s[i];
  isq[i]=(d>0)?(float)(1.0/sqrt((double)d)):0.f;
}

__global__ void k_copyx0(const float* __restrict__ x0, float* __restrict__ out){
  size_t t=(size_t)blockIdx.x*blockDim.x+threadIdx.x;
  if(t>=(size_t)BB*NN*DD) return;
  int d=(int)(t&(DD-1)); size_t bn=t>>10;
  out[bn*OUTD+d]=x0[t];
}

// ---------------- graph conv (writes A into out slab, ld=OUTD) -------------
__global__ void k_conv(const float* __restrict__ xin, const int* __restrict__ ei,
                       const float* __restrict__ degF, const float* __restrict__ isq,
                       const int* __restrict__ rowoff, float* Aout){
  int i=blockIdx.x, b=blockIdx.y;
  __shared__ int sdst[64]; __shared__ float sw[64];
  int r0=rowoff[i], r1=rowoff[i+1];
  int cnt=r1-r0; if(cnt>64) cnt=64;
  float di=degF[i], isqi=isq[i];
  for(int e=threadIdx.x;e<cnt;e+=blockDim.x){
    int dv=ei[2*(r0+e)+1];
    sdst[e]=dv; sw[e]=isqi*isq[dv];
  }
  __syncthreads();
  float cm=((float)(r1-r0))*di/fmaxf(di,1.f);
  const float* xi=xin+((size_t)(b*NN+i))*OUTD;
  float* ao=Aout+((size_t)(b*NN+i))*OUTD;
  for(int d=threadIdx.x; d<DD; d+=blockDim.x){
    float acc=0.f;
    for(int e=0;e<cnt;e++) acc+=sw[e]*xin[((size_t)(b*NN+sdst[e]))*OUTD+d];
    ao[d]=0.5f*acc+0.5f*cm*xi[d];
  }
}

// ---------------- register-resident Householder panel (f32, unchanged) -----
__global__ __launch_bounds__(1024) void k_panelR(float* A, int k0, float* vtws){
  int b=blockIdx.x;
  int m=NN-k0;
  int mq=m>>5;
  int tid=threadIdx.x;
  int c=tid&31, rg=tid>>5;
  float* Ab=A+(size_t)b*BSTR;
  __shared__ float vsh[NN];
  __shared__ float red[32*33];
  __shared__ float s_sh[32];
  __shared__ float taus[32];
  __shared__ float Tsh[32*32];
  __shared__ float meta[4];

  float p[32];
  #pragma unroll
  for(int q=0;q<32;q++){
    p[q]=0.f;
    if(q<mq){
      int r=rg+(q<<5);
      p[q]=Ab[(size_t)(k0+r)*OUTD+k0+c];
    }
  }
  for(int idx=tid; idx<32*32; idx+=1024) Tsh[idx]=0.f;
  __syncthreads();

  #pragma unroll 1
  for(int j=0;j<NB;j++){
    if(c==j){
      float ss=0.f;
      #pragma unroll
      for(int q=0;q<32;q++) if(q<mq){
        int r=rg+(q<<5);
        if(r>j) ss+=p[q]*p[q];
        else if(r==j) meta[2]=p[q];
      }
      red[rg*33+32]=ss;
    }
    __syncthreads();
    if(tid<32){
      float v=red[tid*33+32];
      for(int o=16;o>0;o>>=1) v+=__shfl_xor(v,o,32);
      if(tid==0){
        float alpha=meta[2], ssq=v;
        float tau,scale;
        if(ssq==0.f){ tau=0.f; scale=0.f; }
        else{
          double bn=sqrt((double)alpha*(double)alpha+(double)ssq);
          float beta=(alpha>=0.f)?(float)(-bn):(float)bn;
          tau=(beta-alpha)/beta;
          scale=1.f/(alpha-beta);
        }
        taus[j]=tau; meta[0]=scale;
      }
    }
    __syncthreads();
    float tau=taus[j], scale=meta[0];
    if(c==j){
      #pragma unroll
      for(int q=0;q<32;q++) if(q<mq){
        int r=rg+(q<<5);
        if(r>j){ p[q]*=scale; vsh[r]=p[q]; }
        else if(r==j) vsh[r]=1.f;
      }
    }
    __syncthreads();
    {
      float acc=0.f;
      #pragma unroll
      for(int q=0;q<32;q++) if(q<mq){
        int r=rg+(q<<5);
        if(r>=j) acc+=vsh[r]*p[q];
      }
      red[rg*33+c]=acc;
    }
    __syncthreads();
    {
      int c2=tid>>5, q2=tid&31;
      float v=red[q2*33+c2];
      for(int o=16;o>0;o>>=1) v+=__shfl_xor(v,o,32);
      if(q2==0) s_sh[c2]=v;
    }
    __syncthreads();
    if(c>j){
      float w=tau*s_sh[c];
      #pragma unroll
      for(int q=0;q<32;q++) if(q<mq){
        int r=rg+(q<<5);
        if(r>=j) p[q]-=w*vsh[r];
      }
    }
    if(tid<j){
      float s=0.f;
      for(int q2=tid;q2<j;q2++) s+=Tsh[tid*32+q2]*s_sh[q2];
      Tsh[tid*32+j]=-tau*s;
    } else if(tid==j) Tsh[j*32+j]=tau;
  }
  __syncthreads();

  #pragma unroll
  for(int q=0;q<32;q++) if(q<mq){
    int r=rg+(q<<5);
    float val=(r>c)?p[q]:Tsh[r*32+c];
    Ab[(size_t)(k0+r)*OUTD+k0+c]=val;
  }
  float* vt=vtws+((size_t)b*NPAN+(k0>>5))*2048;
  vt[rg*32+c]=(rg>c)?p[0]:((rg==c)?1.f:0.f);
  vt[1024+tid]=Tsh[tid];
}

// ---------------- block reflector apply via 3-split bf16 MFMA ---------------
// TRANS_T=true :  cols <- (I - V T^T V^T) cols   (geqrf trailing update)
// TRANS_T=false:  cols <- (I - V T   V^T) cols   (orgqr right-apply)
// 6-product emulation (hh,hm,mh,mm,hl,lh) => fp32-equivalent precision.
template<bool TRANS_T>
__global__ __launch_bounds__(256) void k_update(float* A, int col0, int k0){
  int b=blockIdx.y;
  int c0=col0+blockIdx.x*64;
  int m=NN-k0;
  float* Ab=A+(size_t)b*BSTR;
  __shared__ __align__(16) char SM[54400];
  float (*Tsh)[33]=(float(*)[33])(SM);            // 4224
  float (*Wf)[68] =(float(*)[68])(SM+4224);       // 8704 -> 12928
  short (*VTh)[72]=(short(*)[72])(SM+12928);      // 4608 each
  short (*VTm)[72]=(short(*)[72])(SM+17536);
  short (*VTl)[72]=(short(*)[72])(SM+22144);      // -> 26752
  short (*STh)[72]=(short(*)[72])(SM+26752);      // 9216 each
  short (*STm)[72]=(short(*)[72])(SM+35968);
  short (*STl)[72]=(short(*)[72])(SM+45184);      // -> 54400
  // pass2 aliases (regions dead by then):
  short (*W2h)[40]=(short(*)[40])(SM);            // over Tsh/Wf/VTh-head
  short (*W2m)[40]=(short(*)[40])(SM+5120);
  short (*W2l)[40]=(short(*)[40])(SM+10240);      // -> 15360
  short (*V2h)[40]=(short(*)[40])(SM+26752);      // over ST region
  short (*V2m)[40]=(short(*)[40])(SM+31872);
  short (*V2l)[40]=(short(*)[40])(SM+36992);      // -> 42112
  int tid=threadIdx.x;
  int w=tid>>6, lane=tid&63, lr=lane&15, lq=lane>>4;

  for(int idx=tid; idx<1024; idx+=256){
    int q=idx>>5, j=idx&31;
    float v=Ab[(size_t)(k0+q)*OUTD+k0+j];
    Tsh[q][j]=(q<=j)?v:0.f;
  }
  // ---- pass 1: W = V^T * stripe, accumulated over K=m in MFMA ----
  f4v acc0={0.f,0.f,0.f,0.f}, acc1={0.f,0.f,0.f,0.f};
  for(int rt=0;rt<m;rt+=64){
    __syncthreads();
    for(int idx=tid; idx<4096; idx+=256){
      int rr=idx>>6, c=idx&63;
      int r=rt+rr;
      float v=0.f;
      if(r<m && (c0+c)<NN) v=Ab[(size_t)(k0+r)*OUTD+c0+c];
      short h,mm2,l; bsplit3(v,h,mm2,l);
      STh[c][rr]=h; STm[c][rr]=mm2; STl[c][rr]=l;
    }
    for(int idx=tid; idx<2048; idx+=256){
      int rr=idx>>5, j=idx&31;
      int r=rt+rr;
      float v=0.f;
      if(r<m) v=(r<j)?0.f:((r==j)?1.f:Ab[(size_t)(k0+r)*OUTD+k0+j]);
      short h,mm2,l; bsplit3(v,h,mm2,l);
      VTh[j][rr]=h; VTm[j][rr]=mm2; VTl[j][rr]=l;
    }
    __syncthreads();
    #pragma unroll
    for(int ks=0;ks<2;ks++){
      const int ko=ks*32+8*lq;
      b8v a0h=*(const b8v*)&VTh[lr][ko];
      b8v a0m=*(const b8v*)&VTm[lr][ko];
      b8v a0l=*(const b8v*)&VTl[lr][ko];
      b8v a1h=*(const b8v*)&VTh[16+lr][ko];
      b8v a1m=*(const b8v*)&VTm[16+lr][ko];
      b8v a1l=*(const b8v*)&VTl[16+lr][ko];
      b8v bh =*(const b8v*)&STh[w*16+lr][ko];
      b8v bm =*(const b8v*)&STm[w*16+lr][ko];
      b8v bl =*(const b8v*)&STl[w*16+lr][ko];
      // small -> large
      acc0=__builtin_amdgcn_mfma_f32_16x16x32_bf16(a0l,bh,acc0,0,0,0);
      acc0=__builtin_amdgcn_mfma_f32_16x16x32_bf16(a0h,bl,acc0,0,0,0);
      acc0=__builtin_amdgcn_mfma_f32_16x16x32_bf16(a0m,bm,acc0,0,0,0);
      acc0=__builtin_amdgcn_mfma_f32_16x16x32_bf16(a0m,bh,acc0,0,0,0);
      acc0=__builtin_amdgcn_mfma_f32_16x16x32_bf16(a0h,bm,acc0,0,0,0);
      acc0=__builtin_amdgcn_mfma_f32_16x16x32_bf16(a0h,bh,acc0,0,0,0);
      acc1=__builtin_amdgcn_mfma_f32_16x16x32_bf16(a1l,bh,acc1,0,0,0);
      acc1=__builtin_amdgcn_mfma_f32_16x16x32_bf16(a1h,bl,acc1,0,0,0);
      acc1=__builtin_amdgcn_mfma_f32_16x16x32_bf16(a1m,bm,acc1,0,0,0);
      acc1=__builtin_amdgcn_mfma_f32_16x16x32_bf16(a1m,bh,acc1,0,0,0);
      acc1=__builtin_amdgcn_mfma_f32_16x16x32_bf16(a1h,bm,acc1,0,0,0);
      acc1=__builtin_amdgcn_mfma_f32_16x16x32_bf16(a1h,bh,acc1,0,0,0);
    }
  }
  __syncthreads();
  // C/D layout: col=lane&15, row=4*(lane>>4)+i  [verified m89]
  #pragma unroll
  for(int i=0;i<4;i++){
    Wf[4*lq+i][w*16+lr]=acc0[i];
    Wf[16+4*lq+i][w*16+lr]=acc1[i];
  }
  __syncthreads();
  // ---- T apply (f32) ----
  float w2r[8];
  #pragma unroll
  for(int s=0;s<8;s++){
    int idx=tid+s*256;
    int j=idx>>6, c=idx&63;
    float s2=0.f;
    if(TRANS_T){ for(int q=0;q<=j;q++) s2+=Tsh[q][j]*Wf[q][c]; }
    else       { for(int q=j;q<32;q++) s2+=Tsh[j][q]*Wf[q][c]; }
    w2r[s]=s2;
  }
  __syncthreads();
  #pragma unroll
  for(int s=0;s<8;s++){
    int idx=tid+s*256;
    int j=idx>>6, c=idx&63;
    short h,mm2,l; bsplit3(w2r[s],h,mm2,l);
    W2h[c][j]=h; W2m[c][j]=mm2; W2l[c][j]=l;
  }
  // ---- pass 2: stripe -= V * W2 (K=32) ----
  for(int rt=0;rt<m;rt+=64){
    __syncthreads();
    for(int idx=tid; idx<2048; idx+=256){
      int rr=idx>>5, j=idx&31;
      int r=rt+rr;
      float v=0.f;
      if(r<m) v=(r<j)?0.f:((r==j)?1.f:Ab[(size_t)(k0+r)*OUTD+k0+j]);
      short h,mm2,l; bsplit3(v,h,mm2,l);
      V2h[rr][j]=h; V2m[rr][j]=mm2; V2l[rr][j]=l;
    }
    __syncthreads();
    b8v ah=*(const b8v*)&V2h[w*16+lr][8*lq];
    b8v am=*(const b8v*)&V2m[w*16+lr][8*lq];
    b8v al=*(const b8v*)&V2l[w*16+lr][8*lq];
    #pragma unroll
    for(int ct=0;ct<4;ct++){
      if(c0+ct*16<NN){
        b8v bh=*(const b8v*)&W2h[ct*16+lr][8*lq];
        b8v bm=*(const b8v*)&W2m[ct*16+lr][8*lq];
        b8v bl=*(const b8v*)&W2l[ct*16+lr][8*lq];
        f4v acc={0.f,0.f,0.f,0.f};
        acc=__builtin_amdgcn_mfma_f32_16x16x32_bf16(al,bh,acc,0,0,0);
        acc=__builtin_amdgcn_mfma_f32_16x16x32_bf16(ah,bl,acc,0,0,0);
        acc=__builtin_amdgcn_mfma_f32_16x16x32_bf16(am,bm,acc,0,0,0);
        acc=__builtin_amdgcn_mfma_f32_16x16x32_bf16(am,bh,acc,0,0,0);
        acc=__builtin_amdgcn_mfma_f32_16x16x32_bf16(ah,bm,acc,0,0,0);
        acc=__builtin_amdgcn_mfma_f32_16x16x32_bf16(ah,bh,acc,0,0,0);
        int c=c0+ct*16+lr;
        #pragma unroll
        for(int i=0;i<4;i++){
          int r=rt+w*16+4*lq+i;
          if(r<m) Ab[(size_t)(k0+r)*OUTD+c]-=acc[i];
        }
      }
    }
  }
}

// ---------------- parallel Q-panel formation (f32, unchanged) ---------------
__global__ __launch_bounds__(256) void k_formR(float* A, const float* __restrict__ vtws, int k0){
  int b=blockIdx.y;
  int r0=blockIdx.x*128;
  const float* src=vtws+((size_t)b*NPAN+(k0>>5))*2048;
  float* Ab=A+(size_t)b*BSTR;
  __shared__ float Vtop[32][33];
  __shared__ float Tt[32*32];
  __shared__ float S[32][33];
  int tid=threadIdx.x;
  for(int idx=tid; idx<1024; idx+=256){
    Vtop[idx>>5][idx&31]=src[idx];
    Tt[idx]=src[1024+idx];
  }
  __syncthreads();
  for(int idx=tid; idx<1024; idx+=256){
    int q=idx>>5, cc=idx&31;
    float s=0.f;
    for(int pp=q;pp<32;pp++) s+=Tt[q*32+pp]*Vtop[cc][pp];
    S[q][cc]=s;
  }
  __syncthreads();
  int c=tid&31, rw=tid>>5;
  for(int rr=rw; rr<128; rr+=8){
    int r=r0+rr;
    float qv;
    if(r<k0) qv=0.f;
    else{
      int rl=r-k0;
      float s=0.f;
      if(rl<32){
        #pragma unroll
        for(int q=0;q<32;q++) s+=Vtop[rl][q]*S[q][c];
      } else {
        #pragma unroll
        for(int q=0;q<32;q++) s+=Ab[(size_t)r*OUTD+k0+q]*S[q][c];
      }
      qv=((rl==c)?1.f:0.f)-s;
    }
    Ab[(size_t)r*OUTD+k0+c]=qv;
  }
}

extern "C" void kernel_launch(void* const* d_in, const int* in_sizes, int n_in,
                              void* d_out, int out_size, void* d_ws, size_t ws_size,
                              hipStream_t stream){
  const float* x0=(const float*)d_in[0];
  const int* ei=(const int*)d_in[1];
  int E=in_sizes[1]/2;
  float* out=(float*)d_out;
  float* degF=(float*)d_ws;          // N
  float* isq =degF+NN;               // N
  int*  rowoff=(int*)(isq+NN);       // N+1
  float* vtws=(float*)d_ws + 4096;   // B*NPAN*2048 floats = 2MB

  size_t tot=(size_t)BB*NN*DD;
  k_deg_init<<<1,NN,0,stream>>>(degF);
  k_deg<<<(E+255)/256,256,0,stream>>>(ei,degF,E);
  k_scan<<<1,NN,0,stream>>>(degF,isq,rowoff);
  k_copyx0<<<(int)((tot+255)/256),256,0,stream>>>(x0,out);

  for(int l=0;l<LL;l++){
    float* A = out + (size_t)(l+1)*DD;
    k_conv<<<dim3(NN,BB),256,0,stream>>>(out+(size_t)l*DD,ei,degF,isq,rowoff,A);
    for(int kb=0;kb<NPAN;kb++){
      int k0=kb*NB;
      k_panelR<<<BB,1024,0,stream>>>(A,k0,vtws);
      int nc=NN-k0-NB;
      if(nc>0){
        dim3 g((nc+63)/64,BB);
        k_update<true><<<g,256,0,stream>>>(A,k0+NB,k0);
      }
    }
    for(int kb=NPAN-1;kb>=0;kb--){
      int k0=kb*NB;
      int nc=NN-k0-NB;
      if(nc>0){
        dim3 g((nc+63)/64,BB);
        k_update<false><<<g,256,0,stream>>>(A,k0+NB,k0);
      }
      k_formR<<<dim3(NN/128,BB),256,0,stream>>>(A,vtws,k0);
    }
  }
}

// Round 6
// 48377.298 us; speedup vs baseline: 1.1158x; 1.1158x over previous
//
#include <hip/hip_runtime.h>
#include <cmath>

#define NN 1024
#define DD 1024
#define BB 8
#define LL 4
#define OUTD (DD*(LL+1))   // 5120
#define NB 32
#define NPAN 32
#define BSTR ((size_t)NN*OUTD)
#define VSTR 540672ull     // per-batch ws floats for full-V dump (sum of m_i*32)

typedef short b8v __attribute__((ext_vector_type(8)));
typedef float f4v __attribute__((ext_vector_type(4)));

__device__ __forceinline__ unsigned short f2bf(float x){
  unsigned u=__float_as_uint(x);
  return (unsigned short)((u + 0x7FFFu + ((u>>16)&1u))>>16);
}
__device__ __forceinline__ float bf2f(unsigned short h){
  return __uint_as_float(((unsigned)h)<<16);
}
// 3-split: x = h + m + l -> 6-product MFMA == fp32-equivalent precision (validated r5)
__device__ __forceinline__ void bsplit3(float x, short& h, short& m, short& l){
  unsigned short hh=f2bf(x);
  float r1=x-bf2f(hh);
  unsigned short mm=f2bf(r1);
  float r2=r1-bf2f(mm);
  h=(short)hh; m=(short)mm; l=(short)f2bf(r2);
}
__device__ __forceinline__ f4v mfma6(b8v ah,b8v am,b8v al,b8v bh,b8v bm,b8v bl,f4v acc){
  acc=__builtin_amdgcn_mfma_f32_16x16x32_bf16(al,bh,acc,0,0,0);
  acc=__builtin_amdgcn_mfma_f32_16x16x32_bf16(ah,bl,acc,0,0,0);
  acc=__builtin_amdgcn_mfma_f32_16x16x32_bf16(am,bm,acc,0,0,0);
  acc=__builtin_amdgcn_mfma_f32_16x16x32_bf16(am,bh,acc,0,0,0);
  acc=__builtin_amdgcn_mfma_f32_16x16x32_bf16(ah,bm,acc,0,0,0);
  acc=__builtin_amdgcn_mfma_f32_16x16x32_bf16(ah,bh,acc,0,0,0);
  return acc;
}

// ---------------- setup ----------------
__global__ void k_deg_init(float* degF){ degF[threadIdx.x]=0.f; }

__global__ void k_deg(const int* __restrict__ ei, float* __restrict__ degF, int E){
  int e=blockIdx.x*blockDim.x+threadIdx.x;
  if(e<E) atomicAdd(&degF[ei[2*e]],1.f);
}

__global__ void k_scan(const float* __restrict__ degF, float* __restrict__ isq, int* __restrict__ rowoff){
  __shared__ int s[NN];
  int i=threadIdx.x;
  int d=(int)degF[i];
  s[i]=d; __syncthreads();
  for(int off=1;off<NN;off<<=1){
    int v=(i>=off)?s[i-off]:0;
    __syncthreads();
    s[i]+=v;
    __syncthreads();
  }
  if(i==0) rowoff[0]=0;
  rowoff[i+1]=s[i];
  isq[i]=(d>0)?(float)(1.0/sqrt((double)d)):0.f;
}

__global__ void k_copyx0(const float* __restrict__ x0, float* __restrict__ out){
  size_t t=(size_t)blockIdx.x*blockDim.x+threadIdx.x;
  if(t>=(size_t)BB*NN*DD) return;
  int d=(int)(t&(DD-1)); size_t bn=t>>10;
  out[bn*OUTD+d]=x0[t];
}

// ---------------- graph conv ----------------
__global__ void k_conv(const float* __restrict__ xin, const int* __restrict__ ei,
                       const float* __restrict__ degF, const float* __restrict__ isq,
                       const int* __restrict__ rowoff, float* Aout){
  int i=blockIdx.x, b=blockIdx.y;
  __shared__ int sdst[64]; __shared__ float sw[64];
  int r0=rowoff[i], r1=rowoff[i+1];
  int cnt=r1-r0; if(cnt>64) cnt=64;
  float di=degF[i], isqi=isq[i];
  for(int e=threadIdx.x;e<cnt;e+=blockDim.x){
    int dv=ei[2*(r0+e)+1];
    sdst[e]=dv; sw[e]=isqi*isq[dv];
  }
  __syncthreads();
  float cm=((float)(r1-r0))*di/fmaxf(di,1.f);
  const float* xi=xin+((size_t)(b*NN+i))*OUTD;
  float* ao=Aout+((size_t)(b*NN+i))*OUTD;
  for(int d=threadIdx.x; d<DD; d+=blockDim.x){
    float acc=0.f;
    for(int e=0;e<cnt;e++) acc+=sw[e]*xin[((size_t)(b*NN+sdst[e]))*OUTD+d];
    ao[d]=0.5f*acc+0.5f*cm*xi[d];
  }
}

// ---------------- in-register Householder panel factor (512 threads) -------
// thread (c=tid&31, rg=tid>>5 in [0,16)) owns rows rg+16q. Writes full V
// (explicit 0/1 above/on diag) and T (32x32, zero lower) to ws.
__device__ void panel_factor(float* p, int mq, float* vfslot, float* Twslot, char* SM){
  float (*Tsh)[33]=(float(*)[33])(SM);
  float* vsh =(float*)(SM+16896);      // [1024]
  float* red =(float*)(SM+20992);      // [16*33]
  float* s_sh=(float*)(SM+23104);      // [32]
  float* taus=(float*)(SM+23232);      // [32]
  float* meta=(float*)(SM+23360);      // [4]
  int tid=threadIdx.x, c=tid&31, rg=tid>>5;
  for(int idx=tid; idx<32*33; idx+=512) ((float*)Tsh)[idx]=0.f;
  __syncthreads();
  #pragma unroll 1
  for(int j=0;j<NB;j++){
    if(c==j){
      float ss=0.f;
      #pragma unroll
      for(int q=0;q<64;q++) if(q<mq){
        int r=rg+(q<<4);
        if(r>j) ss+=p[q]*p[q];
        else if(r==j) meta[2]=p[q];
      }
      red[rg*33+32]=ss;
    }
    __syncthreads();                                   // B1
    if(tid<16){
      float v=red[tid*33+32];
      #pragma unroll
      for(int o=8;o>0;o>>=1) v+=__shfl_xor(v,o,16);
      if(tid==0){
        float alpha=meta[2], ssq=v, tau, scale;
        if(ssq==0.f){tau=0.f;scale=0.f;}
        else{
          double bn=sqrt((double)alpha*(double)alpha+(double)ssq);
          float beta=(alpha>=0.f)?(float)(-bn):(float)bn; // -sign(alpha)*norm
          tau=(beta-alpha)/beta; scale=1.f/(alpha-beta);
        }
        taus[j]=tau; meta[0]=scale;
      }
    }
    __syncthreads();                                   // B2
    float tau=taus[j], scale=meta[0];
    if(c==j){
      #pragma unroll
      for(int q=0;q<64;q++) if(q<mq){
        int r=rg+(q<<4);
        if(r>j){p[q]*=scale; vsh[r]=p[q];}
        else if(r==j) vsh[r]=1.f;
      }
    }
    __syncthreads();                                   // B3
    {
      float acc=0.f;
      #pragma unroll
      for(int q=0;q<64;q++) if(q<mq){
        int r=rg+(q<<4);
        if(r>=j) acc+=vsh[r]*p[q];
      }
      red[rg*33+c]=acc;
    }
    __syncthreads();                                   // B4
    {
      int c2=tid>>4, q2=tid&15;
      float v=red[q2*33+c2];
      #pragma unroll
      for(int o=8;o>0;o>>=1) v+=__shfl_xor(v,o,16);
      if(q2==0) s_sh[c2]=v;
    }
    __syncthreads();                                   // B5
    if(c>j){
      float wv=tau*s_sh[c];
      #pragma unroll
      for(int q=0;q<64;q++) if(q<mq){
        int r=rg+(q<<4);
        if(r>=j) p[q]-=wv*vsh[r];
      }
    }
    if(tid<j){
      float s=0.f;
      for(int q2=tid;q2<j;q2++) s+=Tsh[tid][q2]*s_sh[q2];
      Tsh[tid][j]=-tau*s;
    } else if(tid==j) Tsh[j][j]=tau;
  }
  __syncthreads();
  #pragma unroll
  for(int q=0;q<64;q++) if(q<mq){
    int r=rg+(q<<4);
    vfslot[(size_t)r*32+c]=(r>c)?p[q]:((r==c)?1.f:0.f);
  }
  for(int idx=tid; idx<1024; idx+=512) Twslot[idx]=Tsh[idx>>5][idx&31];
}

// ---------------- block reflector apply, 3-split MFMA, CS=32, 512 thr ------
// TRANS=true : cols <- (I - V T^T V^T) cols   (geqrf)
// TRANS=false: cols <- (I - V T   V^T) cols   (orgqr)
// V read from ws slot (explicit unit diag / zeros), T from ws.
template<bool TRANS>
__device__ void blk_update(float* Ab, const float* __restrict__ vf, const float* __restrict__ Tb,
                           int k0, int c0, char* SM){
  float (*Tsh)[33]=(float(*)[33])(SM);              // 4224
  float (*Wt)[33] =(float(*)[33])(SM+4224);         // 4224
  float (*Wp)[32][33]=(float(*)[32][33])(SM+8448);  // 2*4224
  short (*W2h)[40]=(short(*)[40])(SM+8448);         // aliases Wp (dead by then)
  short (*W2m)[40]=(short(*)[40])(SM+11008);
  short (*W2l)[40]=(short(*)[40])(SM+13568);
  short (*VTh)[72]=(short(*)[72])(SM+16896);
  short (*VTm)[72]=(short(*)[72])(SM+21504);
  short (*VTl)[72]=(short(*)[72])(SM+26112);
  short (*STh)[72]=(short(*)[72])(SM+30720);
  short (*STm)[72]=(short(*)[72])(SM+35328);
  short (*STl)[72]=(short(*)[72])(SM+39936);        // -> 44544
  short (*V2h)[40]=(short(*)[40])(SM+16896);        // pass2 aliases
  short (*V2m)[40]=(short(*)[40])(SM+22016);
  short (*V2l)[40]=(short(*)[40])(SM+27136);
  int tid=threadIdx.x, w=tid>>6, lane=tid&63, lr=lane&15, lq=lane>>4;
  int m=NN-k0;
  for(int idx=tid; idx<1024; idx+=512) Tsh[idx>>5][idx&31]=Tb[idx];
  // pass 1: W = V^T * stripe (K=m). wave w -> (jt,ct,K-half)
  int jt=w&1, ct=(w>>1)&1, kh=w>>2;
  f4v acc={0.f,0.f,0.f,0.f};
  for(int rt=0; rt<m; rt+=64){
    __syncthreads();
    for(int idx=tid; idx<2048; idx+=512){
      int rr=idx>>5, j=idx&31; int r=rt+rr;
      float v=(r<m)? vf[(size_t)r*32+j] : 0.f;
      short h,mi,lo; bsplit3(v,h,mi,lo);
      VTh[j][rr]=h; VTm[j][rr]=mi; VTl[j][rr]=lo;
    }
    for(int idx=tid; idx<2048; idx+=512){
      int rr=idx>>5, cc=idx&31; int r=rt+rr;
      float v=(r<m)? Ab[(size_t)(k0+r)*OUTD+c0+cc] : 0.f;
      short h,mi,lo; bsplit3(v,h,mi,lo);
      STh[cc][rr]=h; STm[cc][rr]=mi; STl[cc][rr]=lo;
    }
    __syncthreads();
    int ko=kh*32+8*lq;
    b8v ah=*(const b8v*)&VTh[jt*16+lr][ko];
    b8v am=*(const b8v*)&VTm[jt*16+lr][ko];
    b8v al=*(const b8v*)&VTl[jt*16+lr][ko];
    b8v bh=*(const b8v*)&STh[ct*16+lr][ko];
    b8v bm=*(const b8v*)&STm[ct*16+lr][ko];
    b8v bl=*(const b8v*)&STl[ct*16+lr][ko];
    acc=mfma6(ah,am,al,bh,bm,bl,acc);
  }
  __syncthreads();
  // C/D layout: col=lane&15, row=4*(lane>>4)+i [verified m89]
  #pragma unroll
  for(int i=0;i<4;i++) Wp[kh][jt*16+4*lq+i][ct*16+lr]=acc[i];
  __syncthreads();
  #pragma unroll
  for(int s=0;s<2;s++){
    int idx=tid+s*512; int j=idx>>5, cc=idx&31;
    Wt[j][cc]=Wp[0][j][cc]+Wp[1][j][cc];
  }
  __syncthreads();
  float w2r[2];
  #pragma unroll
  for(int s=0;s<2;s++){
    int idx=tid+s*512; int j=idx>>5, cc=idx&31;
    float s2=0.f;
    if(TRANS){ for(int q=0;q<=j;q++) s2+=Tsh[q][j]*Wt[q][cc]; }
    else     { for(int q=j;q<32;q++) s2+=Tsh[j][q]*Wt[q][cc]; }
    w2r[s]=s2;
  }
  __syncthreads();        // all Wt reads done before W2 overwrites Wp region
  #pragma unroll
  for(int s=0;s<2;s++){
    int idx=tid+s*512; int j=idx>>5, cc=idx&31;
    short h,mi,lo; bsplit3(w2r[s],h,mi,lo);
    W2h[cc][j]=h; W2m[cc][j]=mi; W2l[cc][j]=lo;
  }
  // pass 2: stripe -= V * W2. wave w -> (row16 rt4, col16 ct2)
  int rt4=w&3, ct2=w>>2;
  for(int rt=0; rt<m; rt+=64){
    __syncthreads();
    for(int idx=tid; idx<2048; idx+=512){
      int rr=idx>>5, j=idx&31; int r=rt+rr;
      float v=(r<m)? vf[(size_t)r*32+j]:0.f;
      short h,mi,lo; bsplit3(v,h,mi,lo);
      V2h[rr][j]=h; V2m[rr][j]=mi; V2l[rr][j]=lo;
    }
    __syncthreads();
    b8v ah=*(const b8v*)&V2h[rt4*16+lr][8*lq];
    b8v am=*(const b8v*)&V2m[rt4*16+lr][8*lq];
    b8v al=*(const b8v*)&V2l[rt4*16+lr][8*lq];
    b8v bh=*(const b8v*)&W2h[ct2*16+lr][8*lq];
    b8v bm=*(const b8v*)&W2m[ct2*16+lr][8*lq];
    b8v bl=*(const b8v*)&W2l[ct2*16+lr][8*lq];
    f4v a2={0.f,0.f,0.f,0.f};
    a2=mfma6(ah,am,al,bh,bm,bl,a2);
    int ccol=c0+ct2*16+lr;
    #pragma unroll
    for(int i=0;i<4;i++){
      int r=rt+rt4*16+4*lq+i;
      if(r<m) Ab[(size_t)(k0+r)*OUTD+ccol]-=a2[i];
    }
  }
}

// ---------------- fused geqrf step: trailing update(kb) + panel(kb+1) ------
__global__ __launch_bounds__(512) void k_fgeq(float* A, float* vfull, float* Tws, int kb){
  __shared__ __align__(16) char SM[44544];
  int b=blockIdx.y;
  float* Ab=A+(size_t)b*BSTR;
  if(kb>=0){
    int k0=32*kb;
    size_t voff=32768ull*(size_t)kb - 512ull*(size_t)kb*(size_t)(kb-1);
    const float* vf=vfull+(size_t)b*VSTR+voff;
    const float* Tb=Tws+((size_t)b*NPAN+kb)*1024;
    int c0=k0+32+32*blockIdx.x;
    blk_update<true>(Ab,vf,Tb,k0,c0,SM);
    if(blockIdx.x>0) return;
    __syncthreads();
  }
  int kbn=kb+1;
  int k0n=32*kbn;
  int mq=(NN-k0n)>>4;
  int tid=threadIdx.x, c=tid&31, rg=tid>>5;
  float p[64];
  #pragma unroll
  for(int q=0;q<64;q++){
    p[q]=0.f;
    if(q<mq){
      int r=rg+(q<<4);
      p[q]=Ab[(size_t)(k0n+r)*OUTD+k0n+c];
    }
  }
  size_t voffn=32768ull*(size_t)kbn - 512ull*(size_t)kbn*(size_t)(kbn-1);
  panel_factor(p, mq, vfull+(size_t)b*VSTR+voffn, Tws+((size_t)b*NPAN+kbn)*1024, SM);
}

// ---------------- fused orgqr step: form(kb) + right-apply(kb) -------------
__global__ __launch_bounds__(512) void k_ford(float* A, const float* __restrict__ vfull,
                                              const float* __restrict__ Tws, int kb){
  __shared__ __align__(16) char SM[44544];
  int b=blockIdx.y;
  float* Ab=A+(size_t)b*BSTR;
  int k0=32*kb;
  size_t voff=32768ull*(size_t)kb - 512ull*(size_t)kb*(size_t)(kb-1);
  const float* vf=vfull+(size_t)b*VSTR+voff;
  const float* Tb=Tws+((size_t)b*NPAN+kb)*1024;
  if(blockIdx.x>0){
    int c0=k0+32+32*(blockIdx.x-1);
    blk_update<false>(Ab,vf,Tb,k0,c0,SM);
    return;
  }
  // form block: cols [k0,k0+32) <- [0; E - V*(T*Vtop^T)]
  float (*Tsh)[33]=(float(*)[33])(SM);
  float (*Vtf)[33]=(float(*)[33])(SM+4224);
  float (*Sf)[33] =(float(*)[33])(SM+8448);
  int tid=threadIdx.x;
  for(int idx=tid; idx<1024; idx+=512){
    Tsh[idx>>5][idx&31]=Tb[idx];
    Vtf[idx>>5][idx&31]=vf[idx];
  }
  __syncthreads();
  for(int idx=tid; idx<1024; idx+=512){
    int q=idx>>5, cc=idx&31;
    float s=0.f;
    for(int pp=q;pp<32;pp++) s+=Tsh[q][pp]*Vtf[cc][pp];
    Sf[q][cc]=s;
  }
  __syncthreads();
  int c=tid&31, rg=tid>>5;
  for(int r=rg; r<NN; r+=16){
    float outv;
    if(r<k0) outv=0.f;
    else{
      int rl=r-k0;
      const float* vrow=vf+(size_t)rl*32;
      float s=0.f;
      #pragma unroll
      for(int q=0;q<32;q++) s+=vrow[q]*Sf[q][c];
      outv=((rl==c)?1.f:0.f)-s;
    }
    Ab[(size_t)r*OUTD+k0+c]=outv;
  }
}

extern "C" void kernel_launch(void* const* d_in, const int* in_sizes, int n_in,
                              void* d_out, int out_size, void* d_ws, size_t ws_size,
                              hipStream_t stream){
  const float* x0=(const float*)d_in[0];
  const int* ei=(const int*)d_in[1];
  int E=in_sizes[1]/2;
  float* out=(float*)d_out;
  // ws: deg tables (16KB) + T dump (1MB) + full-V dump (17.3MB) = 18.4MB
  float* degF=(float*)d_ws;                      // N
  float* isq =degF+NN;                           // N
  int*  rowoff=(int*)(isq+NN);                   // N+1
  float* Tws  =(float*)d_ws+4096;                // B*32*1024
  float* vfull=Tws+(size_t)BB*NPAN*1024;         // B*VSTR

  size_t tot=(size_t)BB*NN*DD;
  k_deg_init<<<1,NN,0,stream>>>(degF);
  k_deg<<<(E+255)/256,256,0,stream>>>(ei,degF,E);
  k_scan<<<1,NN,0,stream>>>(degF,isq,rowoff);
  k_copyx0<<<(int)((tot+255)/256),256,0,stream>>>(x0,out);

  for(int l=0;l<LL;l++){
    float* A=out+(size_t)(l+1)*DD;
    k_conv<<<dim3(NN,BB),256,0,stream>>>(out+(size_t)l*DD,ei,degF,isq,rowoff,A);
    // geqrf: first panel standalone, then fused update+next-panel
    k_fgeq<<<dim3(1,BB),512,0,stream>>>(A,vfull,Tws,-1);
    for(int kb=0;kb<=30;kb++){
      int nc=NN-32*(kb+1);
      k_fgeq<<<dim3(nc/32,BB),512,0,stream>>>(A,vfull,Tws,kb);
    }
    // orgqr: fused form + right-apply, backward
    for(int kb=NPAN-1;kb>=0;kb--){
      int nc=NN-32*(kb+1);
      k_ford<<<dim3(1+nc/32,BB),512,0,stream>>>(A,vfull,Tws,kb);
    }
  }
}